// Round 3
// baseline (4614.263 us; speedup 1.0000x reference)
//
#include <hip/hip_runtime.h>
#include <hip/hip_bf16.h>

// LSTMClassifier: B=64, T=2000, F=98, H=128, 2 bidirectional layers, FC 256->128->2
// Round-3: rec_kernel restructured (k-sliced lanes + shfl butterfly + 1 barrier/step).
//  - lane (kg,c): kg = k-quarter (32 floats of h), hc = wave*16+c = h-column.
//  - lane computes partial dots for cols {m*128+hc, m=0..3} (i,f,g,o of SAME h-col),
//    butterfly over kg via __shfl_xor(16/32), then the full gate->c->h update in-lane
//    (4x redundant, no cross-wave exchange, no divergence).
//  - h double-buffered in LDS -> single __syncthreads per step.
//  - xg stored gate-interleaved [hc*4+m] so each lane's 4 gates are one 8-B load.

#define TT 2000
#define TC 250
#define NCH (TT / TC)
#define BB 64
#define FF 98
#define HH 128
#define G4 512      // 4*H

typedef __attribute__((ext_vector_type(8))) short short8;
typedef __attribute__((ext_vector_type(4))) float f32x4;

__device__ __forceinline__ float fsig(float x) {
    float e = exp2f(-1.44269504f * x);
    return __builtin_amdgcn_rcpf(1.f + e);
}
__device__ __forceinline__ float ftanh(float x) {
    float ax = fabsf(x);
    float e = exp2f(-2.88539008f * ax);
    float t = (1.f - e) * __builtin_amdgcn_rcpf(1.f + e);
    return x < 0.f ? -t : t;
}
__device__ __forceinline__ float bfbits2f(unsigned u) {
    union { unsigned u; float f; } cv; cv.u = u << 16; return cv.f;
}

// ---------- x [B,1,T,F] f32 -> X0 [T*B][128] bf16 (K padded 98->128) ----------
__global__ void conv_x_kernel(const float* __restrict__ x, __hip_bfloat16* __restrict__ X0) {
    int b = blockIdx.y;
    int t0 = blockIdx.x * 16;
    int tid = threadIdx.x;
    #pragma unroll
    for (int i = 0; i < 8; ++i) {
        int e = tid + i * 256;      // 0..2047 (16 rows x 128 cols)
        int r = e >> 7;
        int f = e & 127;
        float v = (f < FF) ? x[(size_t)b * TT * FF + (size_t)(t0 + r) * FF + f] : 0.f;
        X0[((size_t)(t0 + r) * BB + b) * 128 + f] = __float2bfloat16(v);
    }
}

// ---------- W_ih pair -> bf16 [1024][Kpad], bias = b_ih + b_hh ----------
__global__ void conv_w_kernel(const float* __restrict__ wf, const float* __restrict__ wb,
                              const float* __restrict__ bihf, const float* __restrict__ bhhf,
                              const float* __restrict__ bihb, const float* __restrict__ bhhb,
                              __hip_bfloat16* __restrict__ W, float* __restrict__ bias,
                              int Kin, int Kpad) {
    int j = blockIdx.x;            // 0..1023 ; rows 0-511 fwd, 512-1023 bwd
    int dir = j >> 9;
    int jj = j & 511;
    const float* w = dir ? wb : wf;
    for (int k = threadIdx.x; k < Kpad; k += blockDim.x)
        W[(size_t)j * Kpad + k] = __float2bfloat16(k < Kin ? w[(size_t)jj * Kin + k] : 0.f);
    if (threadIdx.x == 0)
        bias[j] = dir ? (bihb[jj] + bhhb[jj]) : (bihf[jj] + bhhf[jj]);
}

// ---------- chunk GEMM: out[row][colI] = A[Aoff+row][K] * W[c0+col][K]^T + bias ----------
// colI = gate-interleaved: (col&127)*4 + (col>>7). 256 thr, tile 64 rows x 256 cols.
template<int K>
__launch_bounds__(256, 2)
__global__ void gemm_xg_kernel(const short* __restrict__ A,
                               const short* __restrict__ W,
                               const float* __restrict__ bias,
                               __hip_bfloat16* __restrict__ out,
                               int Aoff, int c0) {
    constexpr int KS = K / 32;
    int tid = threadIdx.x;
    int l = tid & 63;
    int wv = tid >> 6;
    int r_loc = blockIdx.x * 64;
    int c_loc = blockIdx.y * 256 + wv * 64;
    int lr = l & 15;
    int lk = (l >> 4) * 8;

    f32x4 acc[4][4];
    #pragma unroll
    for (int a = 0; a < 4; ++a)
        #pragma unroll
        for (int b = 0; b < 4; ++b)
            acc[a][b] = (f32x4){0.f, 0.f, 0.f, 0.f};

    #pragma unroll
    for (int ks = 0; ks < KS; ++ks) {
        short8 af[4], bf[4];
        #pragma unroll
        for (int rt = 0; rt < 4; ++rt)
            af[rt] = *(const short8*)(A + (size_t)(Aoff + r_loc + rt * 16 + lr) * K + ks * 32 + lk);
        #pragma unroll
        for (int ct = 0; ct < 4; ++ct)
            bf[ct] = *(const short8*)(W + (size_t)(c0 + c_loc + ct * 16 + lr) * K + ks * 32 + lk);
        #pragma unroll
        for (int rt = 0; rt < 4; ++rt)
            #pragma unroll
            for (int ct = 0; ct < 4; ++ct)
                acc[rt][ct] = __builtin_amdgcn_mfma_f32_16x16x32_bf16(af[rt], bf[ct], acc[rt][ct], 0, 0, 0);
    }

    #pragma unroll
    for (int ct = 0; ct < 4; ++ct) {
        int col = c_loc + ct * 16 + lr;               // 0..511
        float bv = bias[c0 + col];
        int colI = ((col & 127) << 2) | (col >> 7);   // gate-interleaved
        #pragma unroll
        for (int rt = 0; rt < 4; ++rt) {
            #pragma unroll
            for (int e = 0; e < 4; ++e) {
                int row = r_loc + rt * 16 + (l >> 4) * 4 + e;
                out[(size_t)row * 512 + colI] = __float2bfloat16(acc[rt][ct][e] + bv);
            }
        }
    }
}

// ---------- recurrence chunk: WG per (batch, dir); 512 thr; k-sliced lanes ----------
__launch_bounds__(512, 2)
__global__ void rec_kernel(const __hip_bfloat16* __restrict__ xgF,  // [TC][B][512] interleaved
                           const __hip_bfloat16* __restrict__ xgB,
                           const float* __restrict__ whh_f,         // [512][128]
                           const float* __restrict__ whh_b,
                           __hip_bfloat16* __restrict__ yout,       // [T][B][256] (layer0)
                           float* __restrict__ hstate,              // [2][64][128]
                           float* __restrict__ cstate,
                           int t0f, int writeY, int first) {
    const int b = blockIdx.x;
    const int dir = blockIdx.y;
    const int tid = threadIdx.x;
    const int lane = tid & 63;
    const int w = tid >> 6;          // 0..7
    const int kg = lane >> 4;        // k-quarter 0..3
    const int c = lane & 15;
    const int hc = (w << 4) | c;     // h-column 0..127
    const float* whh = dir ? whh_b : whh_f;
    const __hip_bfloat16* xg = dir ? xgB : xgF;

    // weights for cols {m*128+hc}, k-slice [kg*32, kg*32+32): 128 VGPRs
    float4 wv[4][8];
    #pragma unroll
    for (int m = 0; m < 4; ++m) {
        const float4* wr = (const float4*)(whh + (size_t)(m * 128 + hc) * HH + kg * 32);
        #pragma unroll
        for (int q = 0; q < 8; ++q) wv[m][q] = wr[q];
    }

    // h double buffer, kg-padded: [buf][kg][32+4] -> 4 distinct bank-groups per read
    __shared__ __align__(16) float hbuf[2][4][36];

    const int sidx = (dir * BB + b) * HH;
    float cst = first ? 0.f : cstate[sidx + hc];
    if (kg == 0)
        hbuf[0][hc >> 5][hc & 31] = first ? 0.f : hstate[sidx + hc];
    __syncthreads();

    const int stride = dir ? -(BB * 512) : (BB * 512);
    const __hip_bfloat16* p = xg + (size_t)(dir ? (TC - 1) * BB * 512 : 0)
                                 + (size_t)b * 512 + hc * 4;

    unsigned long long xcur = *(const unsigned long long*)p;  // 4 bf16 gates
    unsigned long long xnxt = 0;
    int cur = 0;
    float hlast = 0.f;

    for (int il = 0; il < TC; ++il) {
        if (il + 1 < TC)
            xnxt = *(const unsigned long long*)(p + stride);

        // ---- partial dot: 8 ds_read_b128 + 128 FMA (16 indep chains) ----
        const float4* hb = (const float4*)(&hbuf[cur][kg][0]);
        float4 hv[8];
        #pragma unroll
        for (int q = 0; q < 8; ++q) hv[q] = hb[q];

        float a0[4], a1[4], a2[4], a3[4];
        #pragma unroll
        for (int m = 0; m < 4; ++m) { a0[m] = a1[m] = a2[m] = a3[m] = 0.f; }
        #pragma unroll
        for (int q = 0; q < 8; ++q) {
            #pragma unroll
            for (int m = 0; m < 4; ++m) {
                a0[m] = fmaf(hv[q].x, wv[m][q].x, a0[m]);
                a1[m] = fmaf(hv[q].y, wv[m][q].y, a1[m]);
                a2[m] = fmaf(hv[q].z, wv[m][q].z, a2[m]);
                a3[m] = fmaf(hv[q].w, wv[m][q].w, a3[m]);
            }
        }

        // ---- butterfly over kg + gates + state update (all lanes, 4x redundant) ----
        float pre[4];
        #pragma unroll
        for (int m = 0; m < 4; ++m) {
            float s = (a0[m] + a1[m]) + (a2[m] + a3[m]);
            s += __shfl_xor(s, 16);
            s += __shfl_xor(s, 32);
            pre[m] = s + bfbits2f((unsigned)((xcur >> (16 * m)) & 0xFFFFu));
        }
        float gi = fsig(pre[0]);
        float gf = fsig(pre[1]);
        float gg = ftanh(pre[2]);
        float go = fsig(pre[3]);
        cst = fmaf(gf, cst, gi * gg);
        float hnew = go * ftanh(cst);
        hlast = hnew;

        if (kg == 0) {
            hbuf[cur ^ 1][hc >> 5][hc & 31] = hnew;
            if (writeY) {
                int t = dir ? (TT - 1 - (t0f + il)) : (t0f + il);
                yout[((size_t)t * BB + b) * 256 + dir * HH + hc] = __float2bfloat16(hnew);
            }
        }
        __syncthreads();
        cur ^= 1;
        xcur = xnxt;
        p += stride;
    }

    if (kg == 0) {
        hstate[sidx + hc] = hlast;
        cstate[sidx + hc] = cst;
    }
}

// ---------- head: out[b] = clf( fc( [h_f, h_b] ) ) ----------
__global__ void fc_kernel(const float* __restrict__ hstate,   // [2][64][128]
                          const float* __restrict__ fcw, const float* __restrict__ fcb,
                          const float* __restrict__ clw, const float* __restrict__ clb,
                          float* __restrict__ out) {
    int b = blockIdx.x;
    int j = threadIdx.x;    // 0..127
    __shared__ float hrow[256];
    __shared__ float feat[128];
    hrow[j]       = hstate[(size_t)b * HH + j];                 // dir 0
    hrow[j + 128] = hstate[(size_t)(BB + b) * HH + j];          // dir 1
    __syncthreads();
    float acc = fcb[j];
    #pragma unroll 4
    for (int k = 0; k < 256; ++k) acc = fmaf(hrow[k], fcw[(size_t)j * 256 + k], acc);
    feat[j] = acc;
    __syncthreads();
    if (j < 2) {
        float o = clb[j];
        #pragma unroll 4
        for (int k = 0; k < 128; ++k) o = fmaf(feat[k], clw[(size_t)j * 128 + k], o);
        out[b * 2 + j] = o;
    }
}

extern "C" void kernel_launch(void* const* d_in, const int* in_sizes, int n_in,
                              void* d_out, int out_size, void* d_ws, size_t ws_size,
                              hipStream_t stream) {
    const float* x        = (const float*)d_in[0];
    const float* w_ih_l0f = (const float*)d_in[1];
    const float* w_hh_l0f = (const float*)d_in[2];
    const float* b_ih_l0f = (const float*)d_in[3];
    const float* b_hh_l0f = (const float*)d_in[4];
    const float* w_ih_l0b = (const float*)d_in[5];
    const float* w_hh_l0b = (const float*)d_in[6];
    const float* b_ih_l0b = (const float*)d_in[7];
    const float* b_hh_l0b = (const float*)d_in[8];
    const float* w_ih_l1f = (const float*)d_in[9];
    const float* w_hh_l1f = (const float*)d_in[10];
    const float* b_ih_l1f = (const float*)d_in[11];
    const float* b_hh_l1f = (const float*)d_in[12];
    const float* w_ih_l1b = (const float*)d_in[13];
    const float* w_hh_l1b = (const float*)d_in[14];
    const float* b_ih_l1b = (const float*)d_in[15];
    const float* b_hh_l1b = (const float*)d_in[16];
    const float* fc_w     = (const float*)d_in[17];
    const float* fc_b     = (const float*)d_in[18];
    const float* clf_w    = (const float*)d_in[19];
    const float* clf_b    = (const float*)d_in[20];

    char* ws = (char*)d_ws;
    size_t off = 0;
    __hip_bfloat16* X0   = (__hip_bfloat16*)(ws + off); off += (size_t)TT * BB * 128 * 2;  // 32.8 MB
    __hip_bfloat16* y0   = (__hip_bfloat16*)(ws + off); off += (size_t)TT * BB * 256 * 2;  // 65.5 MB
    __hip_bfloat16* bufF = (__hip_bfloat16*)(ws + off); off += (size_t)TC * BB * 512 * 2;  // 16.4 MB
    __hip_bfloat16* bufB = (__hip_bfloat16*)(ws + off); off += (size_t)TC * BB * 512 * 2;  // 16.4 MB
    __hip_bfloat16* W0   = (__hip_bfloat16*)(ws + off); off += (size_t)1024 * 128 * 2;
    __hip_bfloat16* W1   = (__hip_bfloat16*)(ws + off); off += (size_t)1024 * 256 * 2;
    float* bias0  = (float*)(ws + off); off += 1024 * 4;
    float* bias1  = (float*)(ws + off); off += 1024 * 4;
    float* hstate = (float*)(ws + off); off += 2 * BB * HH * 4;
    float* cstate = (float*)(ws + off); off += 2 * BB * HH * 4;
    // peak ws ~132 MB

    conv_x_kernel<<<dim3(TT / 16, BB), 256, 0, stream>>>(x, X0);
    conv_w_kernel<<<1024, 128, 0, stream>>>(w_ih_l0f, w_ih_l0b, b_ih_l0f, b_hh_l0f,
                                            b_ih_l0b, b_hh_l0b, W0, bias0, 98, 128);
    conv_w_kernel<<<1024, 256, 0, stream>>>(w_ih_l1f, w_ih_l1b, b_ih_l1f, b_hh_l1f,
                                            b_ih_l1b, b_hh_l1b, W1, bias1, 256, 256);

    dim3 ggrid(TC * BB / 64, 2);

    // layer 0
    for (int k = 0; k < NCH; ++k) {
        gemm_xg_kernel<128><<<ggrid, 256, 0, stream>>>(
            (const short*)X0, (const short*)W0, bias0, bufF, k * TC * BB, 0);
        gemm_xg_kernel<128><<<ggrid, 256, 0, stream>>>(
            (const short*)X0, (const short*)W0, bias0, bufB, (TT - (k + 1) * TC) * BB, 512);
        rec_kernel<<<dim3(BB, 2), 512, 0, stream>>>(
            bufF, bufB, w_hh_l0f, w_hh_l0b, y0, hstate, cstate, k * TC, 1, k == 0);
    }

    // layer 1 (only final h needed by the head)
    for (int k = 0; k < NCH; ++k) {
        gemm_xg_kernel<256><<<ggrid, 256, 0, stream>>>(
            (const short*)y0, (const short*)W1, bias1, bufF, k * TC * BB, 0);
        gemm_xg_kernel<256><<<ggrid, 256, 0, stream>>>(
            (const short*)y0, (const short*)W1, bias1, bufB, (TT - (k + 1) * TC) * BB, 512);
        rec_kernel<<<dim3(BB, 2), 512, 0, stream>>>(
            bufF, bufB, w_hh_l1f, w_hh_l1b, y0 /*unused*/, hstate, cstate, k * TC, 0, k == 0);
    }

    fc_kernel<<<BB, 128, 0, stream>>>(hstate, fc_w, fc_b, clf_w, clf_b, (float*)d_out);
}